// Round 6
// baseline (441.370 us; speedup 1.0000x reference)
//
#include <hip/hip_runtime.h>
#include <hip/hip_fp16.h>
#include <math.h>

#define NN 50000
#define NE 800000
#define GEPS 1e-15f
#define BN_EPS 1e-5f
#define NB 196  // covers NN+1 node entries at 256/block

__device__ __forceinline__ float2 h2f(int bits) {
    __half2 h = *(__half2*)&bits;
    return __half22float2(h);
}
__device__ __forceinline__ int f2h2(float a, float b) {
    __half2 h = __floats2half2_rn(a, b);
    return *(int*)&h;
}

// hist + (block 0) precompute inv[k*3+d] = -0.5/(eps+sigma^2):
// [0..14]=conv1, [15..29]=conv2, [30..32]=skip
__global__ void hist_kernel(const int* __restrict__ ei, int* __restrict__ deg,
                            const float* __restrict__ sig1, const float* __restrict__ sig2,
                            const float* __restrict__ sigs, float* __restrict__ inv) {
    if (blockIdx.x == 0) {
        int t = threadIdx.x;
        if (t < 15)      { float s = sig1[t];      inv[t] = -0.5f / (GEPS + s * s); }
        else if (t < 30) { float s = sig2[t - 15]; inv[t] = -0.5f / (GEPS + s * s); }
        else if (t < 33) { float s = sigs[t - 30]; inv[t] = -0.5f / (GEPS + s * s); }
    }
    int e = blockIdx.x * blockDim.x + threadIdx.x;
    if (e < NE) atomicAdd(&deg[ei[NE + e]], 1);
}

// ---- two-level scan ----
__global__ void block_reduce_kernel(const int* __restrict__ deg, int* __restrict__ bsum) {
    __shared__ int sh[256];
    int t = threadIdx.x;
    int i = blockIdx.x * 256 + t;
    sh[t] = (i < NN) ? deg[i] : 0;
    __syncthreads();
    for (int off = 128; off > 0; off >>= 1) {
        if (t < off) sh[t] += sh[t + off];
        __syncthreads();
    }
    if (t == 0) bsum[blockIdx.x] = sh[0];
}

__global__ void scan_partials_kernel(int* __restrict__ bsum) {
    __shared__ int sh[256];
    int t = threadIdx.x;
    int v = (t < NB) ? bsum[t] : 0;
    sh[t] = v;
    __syncthreads();
    for (int off = 1; off < 256; off <<= 1) {
        int u = (t >= off) ? sh[t - off] : 0;
        __syncthreads();
        sh[t] += u;
        __syncthreads();
    }
    if (t < NB) bsum[t] = sh[t] - v;  // exclusive
}

// writes rowstart[0..NN] (NN+1 entries; rowstart[NN]==NE) and cursor[0..NN-1]
__global__ void block_scan_kernel(const int* __restrict__ deg, const int* __restrict__ bsum,
                                  int* __restrict__ rowstart, int* __restrict__ cursor) {
    __shared__ int sh[256];
    int t = threadIdx.x;
    int i = blockIdx.x * 256 + t;
    int v = (i < NN) ? deg[i] : 0;
    sh[t] = v;
    __syncthreads();
    for (int off = 1; off < 256; off <<= 1) {
        int u = (t >= off) ? sh[t - off] : 0;
        __syncthreads();
        sh[t] += u;
        __syncthreads();
    }
    int excl = sh[t] - v + bsum[blockIdx.x];
    if (i <= NN) rowstart[i] = excl;
    if (i < NN) cursor[i] = excl;
}

// scatter edges into CSR order as TWO 16B records:
// recsA[pos] = {src, (w1_0,w1_1), (w1_2,w1_3), (w1_4, wS)}
// recsB[pos] = {src, (w2_0,w2_1), (w2_2,w2_3), (w2_4, 0)}
__global__ void reorder_kernel(const int* __restrict__ ei, const float* __restrict__ ea,
                               const float* __restrict__ mu1, const float* __restrict__ mu2,
                               const float* __restrict__ mus, const float* __restrict__ inv,
                               int* __restrict__ cursor, int4* __restrict__ recsA,
                               int4* __restrict__ recsB) {
    int e = blockIdx.x * blockDim.x + threadIdx.x;
    if (e >= NE) return;
    int src = ei[e];
    int dst = ei[NE + e];
    float a0 = ea[e * 3 + 0], a1 = ea[e * 3 + 1], a2 = ea[e * 3 + 2];

    float w1[5], w2[5], ws;
#pragma unroll
    for (int k = 0; k < 5; k++) {
        float d0 = a0 - mu1[k * 3 + 0], d1 = a1 - mu1[k * 3 + 1], d2 = a2 - mu1[k * 3 + 2];
        w1[k] = __expf(inv[k * 3] * d0 * d0 + inv[k * 3 + 1] * d1 * d1 + inv[k * 3 + 2] * d2 * d2);
    }
#pragma unroll
    for (int k = 0; k < 5; k++) {
        float d0 = a0 - mu2[k * 3 + 0], d1 = a1 - mu2[k * 3 + 1], d2 = a2 - mu2[k * 3 + 2];
        w2[k] = __expf(inv[15 + k * 3] * d0 * d0 + inv[15 + k * 3 + 1] * d1 * d1 +
                       inv[15 + k * 3 + 2] * d2 * d2);
    }
    {
        float d0 = a0 - mus[0], d1 = a1 - mus[1], d2 = a2 - mus[2];
        ws = __expf(inv[30] * d0 * d0 + inv[31] * d1 * d1 + inv[32] * d2 * d2);
    }

    int pos = atomicAdd(&cursor[dst], 1);
    int4 ra, rb;
    ra.x = src; ra.y = f2h2(w1[0], w1[1]); ra.z = f2h2(w1[2], w1[3]); ra.w = f2h2(w1[4], ws);
    rb.x = src; rb.y = f2h2(w2[0], w2[1]); rb.z = f2h2(w2[2], w2[3]); rb.w = f2h2(w2[4], 0.f);
    recsA[pos] = ra;
    recsB[pos] = rb;
}

// pass A projection: x -> PA[n][192] fp16 (0..159: g1-proj, 160..191: gs-proj),
//                    R1[n][32] fp32 (x@root1+b1), Rs[n][32] fp32 (x@roots+bs). block=256.
__global__ void projA_kernel(const float* __restrict__ x, const float* __restrict__ g1,
                             const float* __restrict__ gs, const float* __restrict__ root1,
                             const float* __restrict__ b1, const float* __restrict__ roots,
                             const float* __restrict__ bs, __half* __restrict__ PA,
                             float* __restrict__ R1, float* __restrict__ Rs) {
    const int t = threadIdx.x;
    float w[32];
    float b = 0.0f;
    if (t < 160) {
#pragma unroll
        for (int i = 0; i < 32; i++) w[i] = g1[i * 160 + t];
    } else if (t < 192) {
        int c = t - 160;
#pragma unroll
        for (int i = 0; i < 32; i++) w[i] = gs[i * 32 + c];
    } else if (t < 224) {
        int c = t - 192;
#pragma unroll
        for (int i = 0; i < 32; i++) w[i] = root1[i * 32 + c];
        b = b1[c];
    } else {
        int c = t - 224;
#pragma unroll
        for (int i = 0; i < 32; i++) w[i] = roots[i * 32 + c];
        b = bs[c];
    }
    __shared__ float xs[8 * 32];
    for (int n0 = blockIdx.x * 8; n0 < NN; n0 += gridDim.x * 8) {
        int rows = NN - n0; if (rows > 8) rows = 8;
        for (int j = t; j < rows * 32; j += 256) xs[j] = x[(size_t)n0 * 32 + j];
        __syncthreads();
        for (int r = 0; r < rows; r++) {
            float acc = b;
#pragma unroll
            for (int i = 0; i < 32; i++) acc += w[i] * xs[r * 32 + i];
            int n = n0 + r;
            if (t < 192) PA[(size_t)n * 192 + t] = __float2half(acc);
            else if (t < 224) R1[(size_t)n * 32 + (t - 192)] = acc;
            else Rs[(size_t)n * 32 + (t - 224)] = acc;
        }
        __syncthreads();
    }
}

// CSR node-gather aggregate (R3 structure, 16B recs). One wave per node; 4 groups of
// 16 lanes; lane owns a channel pair (half2). Fuses mean + root add + BN stats.
template <bool SKIP>
__global__ void agg_kernel(const int4* __restrict__ recs, const int* __restrict__ rowstart,
                           const __half2* __restrict__ P, int strideH2,
                           const float* __restrict__ R, const float* __restrict__ Rs,
                           float* __restrict__ c, float* __restrict__ cs,
                           float* __restrict__ stats) {
    const int tid = blockIdx.x * blockDim.x + threadIdx.x;
    const int lane = threadIdx.x & 63;
    const int grp = lane >> 4;        // 0..3: edge subgroup
    const int ch2 = lane & 15;        // channel pair index
    const int wavesTotal = (gridDim.x * blockDim.x) >> 6;
    const int wid = tid >> 6;

    float s1x = 0.f, s1y = 0.f, q1x = 0.f, q1y = 0.f;
    float ssx = 0.f, ssy = 0.f, qsx = 0.f, qsy = 0.f;

    for (int n = wid; n < NN; n += wavesTotal) {
        const int start = rowstart[n];
        const int end = rowstart[n + 1];
        const int d = end - start;
        float m1x = 0.f, m1y = 0.f, mSx = 0.f, mSy = 0.f;
        for (int i = start + grp; i < end; i += 4) {
            const int4 q = recs[i];
            const __half2* prow = P + (size_t)q.x * strideH2 + ch2;
            float2 p0 = __half22float2(prow[0]);
            float2 p1 = __half22float2(prow[16]);
            float2 p2 = __half22float2(prow[32]);
            float2 p3 = __half22float2(prow[48]);
            float2 p4 = __half22float2(prow[64]);
            float2 u0 = h2f(q.y), u1 = h2f(q.z), u2 = h2f(q.w);
            m1x += u0.x * p0.x + u0.y * p1.x + u1.x * p2.x + u1.y * p3.x + u2.x * p4.x;
            m1y += u0.x * p0.y + u0.y * p1.y + u1.x * p2.y + u1.y * p3.y + u2.x * p4.y;
            if (SKIP) {
                float2 ps = __half22float2(prow[80]);
                mSx += u2.y * ps.x;
                mSy += u2.y * ps.y;
            }
        }
        m1x += __shfl_xor(m1x, 16, 64); m1x += __shfl_xor(m1x, 32, 64);
        m1y += __shfl_xor(m1y, 16, 64); m1y += __shfl_xor(m1y, 32, 64);
        if (SKIP) {
            mSx += __shfl_xor(mSx, 16, 64); mSx += __shfl_xor(mSx, 32, 64);
            mSy += __shfl_xor(mSy, 16, 64); mSy += __shfl_xor(mSy, 32, 64);
        }
        const float invd = 1.0f / fmaxf((float)d, 1.0f);
        if (grp == 0) {
            float2 rv = ((const float2*)(R + (size_t)n * 32))[ch2];
            float vx = m1x * invd + rv.x;
            float vy = m1y * invd + rv.y;
            ((float2*)(c + (size_t)n * 32))[ch2] = make_float2(vx, vy);
            s1x += vx; s1y += vy; q1x += vx * vx; q1y += vy * vy;
            if (SKIP) {
                float2 rs = ((const float2*)(Rs + (size_t)n * 32))[ch2];
                float wx = mSx * invd + rs.x;
                float wy = mSy * invd + rs.y;
                ((float2*)(cs + (size_t)n * 32))[ch2] = make_float2(wx, wy);
                ssx += wx; ssy += wy; qsx += wx * wx; qsy += wy * wy;
            }
        }
    }
    __shared__ float sh[128];
    const int t = threadIdx.x;
    if (t < 128) sh[t] = 0.f;
    __syncthreads();
    if (grp == 0) {
        atomicAdd(&sh[2 * ch2], s1x);       atomicAdd(&sh[2 * ch2 + 1], s1y);
        atomicAdd(&sh[32 + 2 * ch2], q1x);  atomicAdd(&sh[32 + 2 * ch2 + 1], q1y);
        if (SKIP) {
            atomicAdd(&sh[64 + 2 * ch2], ssx);  atomicAdd(&sh[64 + 2 * ch2 + 1], ssy);
            atomicAdd(&sh[96 + 2 * ch2], qsx);  atomicAdd(&sh[96 + 2 * ch2 + 1], qsy);
        }
    }
    __syncthreads();
    if (SKIP) { if (t < 128) atomicAdd(&stats[t], sh[t]); }
    else      { if (t < 64)  atomicAdd(&stats[t], sh[t]); }
}

// FUSED apply1 + projB: h = elu(bn(c1)) computed in LDS (never materialized),
// s = bn(cs) -> sbuf, then PB[n][160] = h@g2 (fp16), R2[n][32] = h@root2+b2. block=192.
__global__ void fuse1_kernel(const float* __restrict__ c1, const float* __restrict__ cs,
                             const float* __restrict__ stats, const float* __restrict__ gam1,
                             const float* __restrict__ bet1, const float* __restrict__ gams,
                             const float* __restrict__ bets, const float* __restrict__ g2,
                             const float* __restrict__ root2, const float* __restrict__ b2,
                             __half* __restrict__ PB, float* __restrict__ R2,
                             float* __restrict__ sbuf) {
    const int t = threadIdx.x;
    float w[32];
    float b = 0.0f;
    if (t < 160) {
#pragma unroll
        for (int i = 0; i < 32; i++) w[i] = g2[i * 160 + t];
    } else {
        int c = t - 160;
#pragma unroll
        for (int i = 0; i < 32; i++) w[i] = root2[i * 32 + c];
        b = b2[c];
    }
    __shared__ float bscale[32], bshift[32], sscale[32], sshift[32];
    if (t < 32) {
        const float invN = 1.0f / (float)NN;
        float m = stats[t] * invN;
        float v = stats[32 + t] * invN - m * m;
        float sc = gam1[t] * rsqrtf(v + BN_EPS);
        bscale[t] = sc;
        bshift[t] = bet1[t] - m * sc;
        float ms = stats[64 + t] * invN;
        float vs = stats[96 + t] * invN - ms * ms;
        float scs = gams[t] * rsqrtf(vs + BN_EPS);
        sscale[t] = scs;
        sshift[t] = bets[t] - ms * scs;
    }
    __shared__ float xs[8 * 32];
    __syncthreads();
    for (int n0 = blockIdx.x * 8; n0 < NN; n0 += gridDim.x * 8) {
        int rows = NN - n0; if (rows > 8) rows = 8;
        for (int j = t; j < rows * 32; j += 192) {
            int ch = j & 31;
            size_t idx = (size_t)n0 * 32 + j;
            float hv = bscale[ch] * c1[idx] + bshift[ch];
            xs[j] = hv > 0.f ? hv : (__expf(hv) - 1.f);
            sbuf[idx] = sscale[ch] * cs[idx] + sshift[ch];
        }
        __syncthreads();
        for (int r = 0; r < rows; r++) {
            float acc = b;
#pragma unroll
            for (int i = 0; i < 32; i++) acc += w[i] * xs[r * 32 + i];
            int n = n0 + r;
            if (t < 160) PB[(size_t)n * 160 + t] = __float2half(acc);
            else R2[(size_t)n * 32 + (t - 160)] = acc;
        }
        __syncthreads();
    }
}

// out = elu(bn(c2) + s)
__global__ void apply2_kernel(const float* __restrict__ c2, const float* __restrict__ s_in,
                              const float* __restrict__ stats, const float* __restrict__ gam2,
                              const float* __restrict__ bet2, float* __restrict__ out) {
    int idx = blockIdx.x * blockDim.x + threadIdx.x;
    if (idx >= NN * 32) return;
    int ch = idx & 31;
    const float invN = 1.0f / (float)NN;
    float m = stats[ch] * invN;
    float v = stats[32 + ch] * invN - m * m;
    float o = gam2[ch] * (c2[idx] - m) * rsqrtf(v + BN_EPS) + bet2[ch] + s_in[idx];
    out[idx] = o > 0.f ? o : (__expf(o) - 1.f);
}

extern "C" void kernel_launch(void* const* d_in, const int* in_sizes, int n_in,
                              void* d_out, int out_size, void* d_ws, size_t ws_size,
                              hipStream_t stream) {
    const float* x     = (const float*)d_in[0];
    const float* ea    = (const float*)d_in[1];
    const float* g1    = (const float*)d_in[2];
    const float* mu1   = (const float*)d_in[3];
    const float* sig1  = (const float*)d_in[4];
    const float* root1 = (const float*)d_in[5];
    const float* b1    = (const float*)d_in[6];
    const float* gam1  = (const float*)d_in[7];
    const float* bet1  = (const float*)d_in[8];
    const float* g2    = (const float*)d_in[9];
    const float* mu2   = (const float*)d_in[10];
    const float* sig2  = (const float*)d_in[11];
    const float* root2 = (const float*)d_in[12];
    const float* b2    = (const float*)d_in[13];
    const float* gam2  = (const float*)d_in[14];
    const float* bet2  = (const float*)d_in[15];
    const float* gs    = (const float*)d_in[16];
    const float* mus   = (const float*)d_in[17];
    const float* sigs  = (const float*)d_in[18];
    const float* roots = (const float*)d_in[19];
    const float* bs    = (const float*)d_in[20];
    const float* gams  = (const float*)d_in[21];
    const float* bets  = (const float*)d_in[22];
    const int*   ei    = (const int*)d_in[23];
    float* out = (float*)d_out;

    // ---- workspace layout ----
    char* w = (char*)d_ws;
    __half* PA   = (__half*)w;      w += (size_t)NN * 192 * 2;  // 19.2 MB (reused as PB)
    float*  R1   = (float*)w;       w += (size_t)NN * 32 * 4;   // (reused as R2)
    float*  Rs   = (float*)w;       w += (size_t)NN * 32 * 4;
    float*  c1   = (float*)w;       w += (size_t)NN * 32 * 4;   // (reused as c2)
    float*  cs   = (float*)w;       w += (size_t)NN * 32 * 4;
    float*  sbuf = (float*)w;       w += (size_t)NN * 32 * 4;
    int4*   recsA = (int4*)w;       w += (size_t)NE * 16;       // 12.8 MB
    int4*   recsB = (int4*)w;       w += (size_t)NE * 16;       // 12.8 MB
    int*    deg  = (int*)w;         w += (size_t)NN * 4;
    float*  stats = (float*)w;      w += 256 * 4;               // [0..127]=pass A, [128..191]=pass B
    int*    rowstart = (int*)w;     w += (size_t)(NN + 1) * 4;
    int*    cursor   = (int*)w;     w += (size_t)NN * 4;
    int*    bsum = (int*)w;         w += 256 * 4;
    float*  inv  = (float*)w;       w += 64 * 4;

    const int edgeBlocks  = (NE + 255) / 256;
    const int applyBlocks = (NN * 32 + 255) / 256;

    // deg and stats are contiguous -> one memset
    hipMemsetAsync(deg, 0, (size_t)NN * 4 + 256 * 4, stream);

    // ---- CSR build (once, shared by all 3 convs) ----
    hist_kernel<<<edgeBlocks, 256, 0, stream>>>(ei, deg, sig1, sig2, sigs, inv);
    block_reduce_kernel<<<NB, 256, 0, stream>>>(deg, bsum);
    scan_partials_kernel<<<1, 256, 0, stream>>>(bsum);
    block_scan_kernel<<<NB, 256, 0, stream>>>(deg, bsum, rowstart, cursor);
    reorder_kernel<<<edgeBlocks, 256, 0, stream>>>(ei, ea, mu1, mu2, mus, inv, cursor,
                                                   recsA, recsB);

    // ---- pass A: conv1 + skip fused ----
    projA_kernel<<<512, 256, 0, stream>>>(x, g1, gs, root1, b1, roots, bs, PA, R1, Rs);
    agg_kernel<true><<<2048, 256, 0, stream>>>(recsA, rowstart, (const __half2*)PA, 96,
                                               R1, Rs, c1, cs, stats);
    // ---- fused: h=elu(bn(c1)) -> PB/R2 ; s=bn(cs) -> sbuf ----
    fuse1_kernel<<<512, 192, 0, stream>>>(c1, cs, stats, gam1, bet1, gams, bets,
                                          g2, root2, b2, PA, R1, sbuf);  // PA/R1 reused
    // ---- pass B: conv2, then out = elu(bn(c2) + s) ----
    agg_kernel<false><<<2048, 256, 0, stream>>>(recsB, rowstart, (const __half2*)PA, 80,
                                                R1, nullptr, c1, nullptr, stats + 128);
    apply2_kernel<<<applyBlocks, 256, 0, stream>>>(c1, sbuf, stats + 128, gam2, bet2, out);
}